// Round 11
// baseline (4351.177 us; speedup 1.0000x reference)
//
#include <hip/hip_runtime.h>
#include <hip/hip_bf16.h>

#define BB 4
#define MM 8192
#define SS1 2048
#define SS2 512

using ull = unsigned long long;

// ---------------- local branch MLP: pos -> 64 -> 64 -> 128 (tanh each) ----------------
__global__ __launch_bounds__(256) void local_mlp_kernel(
    const float* __restrict__ pos,
    const float* __restrict__ w0, const float* __restrict__ b0,
    const float* __restrict__ w1, const float* __restrict__ b1,
    const float* __restrict__ w2, const float* __restrict__ b2,
    float* __restrict__ out) {
  __shared__ float p[2][3];
  __shared__ float h0[2][64];
  __shared__ float h1[2][64];
  int t = threadIdx.x;
  size_t pid0 = (size_t)blockIdx.x * 2;
  if (t < 6) {
    int pp = t / 3, j = t % 3;
    p[pp][j] = pos[(pid0 + pp) * 3 + j];
  }
  __syncthreads();
  if (t < 128) {
    int pp = t >> 6, c = t & 63;
    float acc = b0[c];
    #pragma unroll
    for (int j = 0; j < 3; ++j) acc += p[pp][j] * w0[j * 64 + c];
    h0[pp][c] = tanhf(acc);
  }
  __syncthreads();
  if (t < 128) {
    int pp = t >> 6, c = t & 63;
    float acc = b1[c];
    #pragma unroll
    for (int j = 0; j < 64; ++j) acc += h0[pp][j] * w1[j * 64 + c];
    h1[pp][c] = tanhf(acc);
  }
  __syncthreads();
  {
    int pp = t >> 7, c = t & 127;
    float acc = b2[c];
    #pragma unroll
    for (int j = 0; j < 64; ++j) acc += h1[pp][j] * w2[j * 128 + c];
    out[(pid0 + pp) * 128 + c] = tanhf(acc);
  }
}

// ---------------- DPP helpers ----------
template <int CTRL>
__device__ __forceinline__ void dpp_max_step(ull& k) {
  unsigned lo = (unsigned)k, hi = (unsigned)(k >> 32);
  unsigned plo = (unsigned)__builtin_amdgcn_update_dpp(0, (int)lo, CTRL, 0xF, 0xF, true);
  unsigned phi = (unsigned)__builtin_amdgcn_update_dpp(0, (int)hi, CTRL, 0xF, 0xF, true);
  ull pk = ((ull)phi << 32) | plo;
  if (pk > k) k = pk;
}

// full-wave max, result in lane 63
__device__ __forceinline__ void wave_max_u64(ull& k) {
  dpp_max_step<0x111>(k);  // row_shr:1
  dpp_max_step<0x112>(k);  // row_shr:2
  dpp_max_step<0x114>(k);  // row_shr:4
  dpp_max_step<0x118>(k);  // row_shr:8
  dpp_max_step<0x142>(k);  // row_bcast:15
  dpp_max_step<0x143>(k);  // row_bcast:31 -> lane63 = wave max
}

// 16-lane (one row) max, result in lane 15
__device__ __forceinline__ void row16_max_u64(ull& k) {
  dpp_max_step<0x111>(k);
  dpp_max_step<0x112>(k);
  dpp_max_step<0x114>(k);
  dpp_max_step<0x118>(k);
}

// ---------------- farthest point sampling ----------------
// One block per batch, 1024 threads, E = MP/1024 points per thread held in
// REGISTERS (E=8 -> 32 VGPRs: R4 proved the allocator keeps this resident;
// E>=16 always spilled). Exact f32 numpy semantics: contract off, x*x then
// +y*y then +z*z; argmax ties -> lowest index via key (d2_bits<<32)|~idx.
// Block reduce: per-wave DPP -> 16 keys in LDS -> every wave reads them with
// ONE predicated ds_read_b64 (lanes 0..15) + 4 DPP steps + shfl broadcast.
// Winner coords: wave-uniform readfirstlane -> scalar L2 fetch.
template <int MP, int NSEL, int THREADS>
__global__ __launch_bounds__(THREADS) void fps_kernel(const float* __restrict__ pts,
                                                      float* __restrict__ cen) {
  constexpr int E = MP / THREADS;
  constexpr int W = THREADS / 64;
  __shared__ ull kb[2][W];
  int t = threadIdx.x;
  int lane = t & 63, wv = t >> 6;
  int b = blockIdx.x;
  const float* p = pts + (size_t)b * MP * 3;
  float* c_out = cen + (size_t)b * NSEL * 3;
  float px[E], py[E], pz[E], dd[E];
  int base = t * E;
  #pragma unroll
  for (int e = 0; e < E; ++e) {
    px[e] = p[(base + e) * 3 + 0];
    py[e] = p[(base + e) * 3 + 1];
    pz[e] = p[(base + e) * 3 + 2];
    dd[e] = INFINITY;
  }
  float cx = p[0], cy = p[1], cz = p[2];
  if (t == 0) { c_out[0] = cx; c_out[1] = cy; c_out[2] = cz; }
  int par = 0;
  for (int it = 1; it < NSEL; ++it) {
    float bd = -1.0f;
    int bidx = 0;
    {
      #pragma clang fp contract(off)
      #pragma unroll
      for (int e = 0; e < E; ++e) {
        float dx = px[e] - cx, dy = py[e] - cy, dz = pz[e] - cz;
        float nd = dx * dx;
        nd += dy * dy;
        nd += dz * dz;
        float d = fminf(dd[e], nd);
        dd[e] = d;
        if (d > bd) { bd = d; bidx = base + e; }  // strict > keeps lowest index
      }
    }
    ull k = ((ull)__float_as_uint(bd) << 32) | (unsigned)(~bidx);
    wave_max_u64(k);
    if (lane == 63) kb[par][wv] = k;
    __syncthreads();
    ull v = 0;
    if (lane < W) v = kb[par][lane];  // one predicated ds_read_b64 per wave
    row16_max_u64(v);                 // lane15 = block max
    ull g = __shfl(v, 15, 64);
    int widx = __builtin_amdgcn_readfirstlane((int)(~(unsigned)g));
    const float* cp = p + (size_t)widx * 3;  // wave-uniform -> scalar load
    cx = cp[0]; cy = cp[1]; cz = cp[2];
    if (t == 0) {
      c_out[it * 3 + 0] = cx;
      c_out[it * 3 + 1] = cy;
      c_out[it * 3 + 2] = cz;
    }
    par ^= 1;
  }
}

// ---------------- ball query: 64 nearest with d2 <= R2, ties by lower index ----------------
// Output indices as i16 (values -1..8191 fit losslessly).
template <int MP>
__global__ __launch_bounds__(256) void nbr_kernel(const float* __restrict__ pts,
                                                  const float* __restrict__ cen, int S,
                                                  float R2, short* __restrict__ nbr) {
  constexpr int CAP = 1024;
  __shared__ ull buf[4][CAP];
  int t = threadIdx.x;
  int wv = t >> 6, lane = t & 63;
  int gw = blockIdx.x * 4 + wv;
  int b = gw / S, s = gw % S;
  const float* p = pts + (size_t)b * MP * 3;
  const float* c = cen + ((size_t)b * S + s) * 3;
  float cx = c[0], cy = c[1], cz = c[2];
  ull* bw = buf[wv];
  int cnt = 0;
  {
    #pragma clang fp contract(off)
    for (int i0 = 0; i0 < MP; i0 += 64) {
      int i = i0 + lane;
      float dx = p[i * 3 + 0] - cx;
      float dy = p[i * 3 + 1] - cy;
      float dz = p[i * 3 + 2] - cz;
      float d2 = dx * dx;
      d2 += dy * dy;
      d2 += dz * dz;
      bool in = (d2 <= R2);
      ull mask = __ballot(in);
      if (in) {
        int off = __popcll(mask & ((1ull << lane) - 1ull));
        int pos = cnt + off;
        if (pos < CAP)
          bw[pos] = ((ull)__float_as_uint(d2) << 32) | (unsigned)i;
      }
      cnt += __popcll(mask);
    }
  }
  if (cnt > CAP) cnt = CAP;
  __syncthreads();  // uniform; ensures LDS writes visible
  int out = -1;
  if (cnt <= 64) {
    if (lane < cnt) out = (int)(unsigned)bw[lane];
  } else {
    for (int r = 0; r < 64; ++r) {
      ull mk = ~0ull;
      int mj = -1;
      for (int j = lane; j < cnt; j += 64) {
        ull v = bw[j];
        if (v < mk) { mk = v; mj = j; }
      }
      ull kc = ~mk;
      wave_max_u64(kc);
      ull g = ~__shfl(kc, 63, 64);
      if (mk == g && mj >= 0) bw[mj] = ~0ull;  // unique keys -> exactly one owner
      asm volatile("s_waitcnt lgkmcnt(0)" ::: "memory");
      if (lane == r) out = (int)(unsigned)g;
    }
  }
  nbr[((size_t)b * S + s) * 64 + lane] = (short)out;
}

// ---------------- SA1 grouped MLP: feats[64][9] -> 64 -> 128, masked max over K ----------------
// layer2 register-tiled 8k x 4ch; tanh/bias deferred past the masked max (exact).
__global__ __launch_bounds__(256, 4) void group1_kernel(
    const float* __restrict__ pos, const float* __restrict__ x,
    const float* __restrict__ c1, const short* __restrict__ nbr,
    const float* __restrict__ w0, const float* __restrict__ b0,
    const float* __restrict__ w1, const float* __restrict__ b1,
    float* __restrict__ h1out) {
  __shared__ float feats[64][12];
  __shared__ float hbuf[64][68];
  __shared__ float Mred[8][128];
  __shared__ int nb[64];
  __shared__ float cc[3];
  int t = threadIdx.x;
  int bs = blockIdx.x;  // b*S1 + s
  int b = bs >> 11;
  if (t < 64) nb[t] = (int)nbr[(size_t)bs * 64 + t];
  if (t < 3) cc[t] = c1[(size_t)bs * 3 + t];
  __syncthreads();
  if (t < 64) {
    int n = nb[t];
    int ni = ((unsigned)n < (unsigned)MM) ? n : 0;  // clamp: replay-safe
    const float* pp = pos + ((size_t)b * MM + ni) * 3;
    const float* xx = x + ((size_t)b * MM + ni) * 3;
    float p0 = pp[0], p1 = pp[1], p2 = pp[2];
    feats[t][0] = p0; feats[t][1] = p1; feats[t][2] = p2;
    feats[t][3] = xx[0]; feats[t][4] = xx[1]; feats[t][5] = xx[2];
    feats[t][6] = p0 - cc[0]; feats[t][7] = p1 - cc[1]; feats[t][8] = p2 - cc[2];
  }
  __syncthreads();
  // layer1: 9 -> 64; thread (k = t>>2, q = t&3) computes 16 channels
  {
    int k = t >> 2, q = t & 3;
    float acc[16];
    #pragma unroll
    for (int i = 0; i < 16; ++i) acc[i] = b0[q * 16 + i];
    #pragma unroll
    for (int j = 0; j < 9; ++j) {
      float f = feats[k][j];
      const float4* wr = (const float4*)(w0 + j * 64 + q * 16);
      #pragma unroll
      for (int i = 0; i < 4; ++i) {
        float4 wvv = wr[i];
        acc[4 * i + 0] += f * wvv.x;
        acc[4 * i + 1] += f * wvv.y;
        acc[4 * i + 2] += f * wvv.z;
        acc[4 * i + 3] += f * wvv.w;
      }
    }
    #pragma unroll
    for (int i = 0; i < 16; ++i) hbuf[k][q * 16 + i] = tanhf(acc[i]);
  }
  __syncthreads();
  // layer2: hidden[64][64] x W1[64][128], masked PRE-ACT max over k
  {
    int kt = t >> 5;  // 0..7
    int ct = t & 31;  // 0..31
    float acc[8][4];
    #pragma unroll
    for (int a = 0; a < 8; ++a)
      #pragma unroll
      for (int ci = 0; ci < 4; ++ci) acc[a][ci] = 0.f;
    const float* wbase = w1 + ct * 4;
    for (int j = 0; j < 64; j += 2) {
      float2 fv[8];
      #pragma unroll
      for (int kk = 0; kk < 8; ++kk)
        fv[kk] = *(const float2*)&hbuf[kt * 8 + kk][j];
      float wja[4], wjb[4];
      *(float4*)&wja[0] = *(const float4*)(wbase + (size_t)j * 128);
      *(float4*)&wjb[0] = *(const float4*)(wbase + (size_t)(j + 1) * 128);
      #pragma unroll
      for (int kk = 0; kk < 8; ++kk)
        #pragma unroll
        for (int ci = 0; ci < 4; ++ci) {
          acc[kk][ci] += fv[kk].x * wja[ci];
          acc[kk][ci] += fv[kk].y * wjb[ci];
        }
    }
    float m[4];
    #pragma unroll
    for (int ci = 0; ci < 4; ++ci) m[ci] = -INFINITY;
    #pragma unroll
    for (int kk = 0; kk < 8; ++kk) {
      if (nb[kt * 8 + kk] >= 0) {
        #pragma unroll
        for (int ci = 0; ci < 4; ++ci) m[ci] = fmaxf(m[ci], acc[kk][ci]);
      }
    }
    #pragma unroll
    for (int ci = 0; ci < 4; ++ci) Mred[kt][ct * 4 + ci] = m[ci];
  }
  __syncthreads();
  if (t < 128) {
    float mx = Mred[0][t];
    #pragma unroll
    for (int r = 1; r < 8; ++r) mx = fmaxf(mx, Mred[r][t]);
    h1out[(size_t)bs * 128 + t] = tanhf(mx + b1[t]);  // bias+tanh after max: exact
  }
}

// ---------------- SA2 grouped MLP: feats[64][131] -> 128 -> 256, masked max over K ----------------
__global__ __launch_bounds__(256, 4) void group2_kernel(
    const float* __restrict__ h1, const float* __restrict__ c1,
    const float* __restrict__ c2, const short* __restrict__ nbr,
    const float* __restrict__ w0, const float* __restrict__ b0,
    const float* __restrict__ w1, const float* __restrict__ b1,
    float* __restrict__ h2out) {
  __shared__ float fb[64][132];  // feats (131) then reused as hidden (128)
  __shared__ float Mred[8][256];
  __shared__ int nb[64];
  __shared__ float cc[3];
  int t = threadIdx.x;
  int bs = blockIdx.x;  // b*S2 + s
  int b = bs >> 9;
  if (t < 64) nb[t] = (int)nbr[(size_t)bs * 64 + t];
  if (t < 3) cc[t] = c2[(size_t)bs * 3 + t];
  __syncthreads();
  {
    int k = t >> 2, q = t & 3;
    int n = nb[k];
    int ni = ((unsigned)n < (unsigned)SS1) ? n : 0;  // clamp: replay-safe
    const float* hrow = h1 + ((size_t)b * SS1 + ni) * 128;
    #pragma unroll
    for (int i = 0; i < 32; ++i) fb[k][q * 32 + i] = hrow[q * 32 + i];
    if (q == 0) {
      const float* pr = c1 + ((size_t)b * SS1 + ni) * 3;
      fb[k][128] = pr[0] - cc[0];
      fb[k][129] = pr[1] - cc[1];
      fb[k][130] = pr[2] - cc[2];
    }
  }
  __syncthreads();
  float acc1[32];
  {
    int k = t >> 2, q = t & 3;
    #pragma unroll
    for (int i = 0; i < 32; ++i) acc1[i] = b0[q * 32 + i];
    for (int j = 0; j < 131; ++j) {
      float f = fb[k][j];
      const float4* wr = (const float4*)(w0 + (size_t)j * 128 + q * 32);
      #pragma unroll
      for (int i = 0; i < 8; ++i) {
        float4 wvv = wr[i];
        acc1[4 * i + 0] += f * wvv.x;
        acc1[4 * i + 1] += f * wvv.y;
        acc1[4 * i + 2] += f * wvv.z;
        acc1[4 * i + 3] += f * wvv.w;
      }
    }
  }
  __syncthreads();
  {
    int k = t >> 2, q = t & 3;
    #pragma unroll
    for (int i = 0; i < 32; ++i) fb[k][q * 32 + i] = tanhf(acc1[i]);
  }
  __syncthreads();
  {
    int kt = t >> 5;  // 0..7
    int ct = t & 31;  // 0..31
    float acc[8][8];
    #pragma unroll
    for (int a = 0; a < 8; ++a)
      #pragma unroll
      for (int c2i = 0; c2i < 8; ++c2i) acc[a][c2i] = 0.f;
    const float* wbase = w1 + ct * 8;
    for (int j = 0; j < 128; j += 2) {
      float2 fv[8];
      #pragma unroll
      for (int kk = 0; kk < 8; ++kk)
        fv[kk] = *(const float2*)&fb[kt * 8 + kk][j];
      float wja[8], wjb[8];
      const float4* wp0 = (const float4*)(wbase + (size_t)j * 256);
      const float4* wp1 = (const float4*)(wbase + (size_t)(j + 1) * 256);
      *(float4*)&wja[0] = wp0[0];
      *(float4*)&wja[4] = wp0[1];
      *(float4*)&wjb[0] = wp1[0];
      *(float4*)&wjb[4] = wp1[1];
      #pragma unroll
      for (int kk = 0; kk < 8; ++kk)
        #pragma unroll
        for (int ci = 0; ci < 8; ++ci) {
          acc[kk][ci] += fv[kk].x * wja[ci];
          acc[kk][ci] += fv[kk].y * wjb[ci];
        }
    }
    float m[8];
    #pragma unroll
    for (int ci = 0; ci < 8; ++ci) m[ci] = -INFINITY;
    #pragma unroll
    for (int kk = 0; kk < 8; ++kk) {
      if (nb[kt * 8 + kk] >= 0) {
        #pragma unroll
        for (int ci = 0; ci < 8; ++ci) m[ci] = fmaxf(m[ci], acc[kk][ci]);
      }
    }
    #pragma unroll
    for (int ci = 0; ci < 8; ++ci) Mred[kt][ct * 8 + ci] = m[ci];
  }
  __syncthreads();
  if (t < 256) {
    float mx = Mred[0][t];
    #pragma unroll
    for (int r = 1; r < 8; ++r) mx = fmaxf(mx, Mred[r][t]);
    h2out[(size_t)bs * 256 + t] = tanhf(mx + b1[t]);  // bias+tanh after max: exact
  }
}

// ---------------- global max over centers ----------------
__global__ __launch_bounds__(256) void gmax_kernel(const float* __restrict__ h2,
                                                   float* __restrict__ out) {
  int b = blockIdx.x, c = threadIdx.x;
  float mx = -INFINITY;
  for (int s = 0; s < SS2; ++s)
    mx = fmaxf(mx, h2[((size_t)b * SS2 + s) * 256 + c]);
  out[(size_t)BB * MM * 128 + b * 256 + c] = mx;
}

extern "C" void kernel_launch(void* const* d_in, const int* in_sizes, int n_in,
                              void* d_out, int out_size, void* d_ws, size_t ws_size,
                              hipStream_t stream) {
  // Reference is pure float32: all inputs AND the output buffer are f32.
  const float* x    = (const float*)d_in[0];
  const float* pos  = (const float*)d_in[1];
  const float* lw0  = (const float*)d_in[2];
  const float* lb0  = (const float*)d_in[3];
  const float* lw1  = (const float*)d_in[4];
  const float* lb1  = (const float*)d_in[5];
  const float* lw2  = (const float*)d_in[6];
  const float* lb2  = (const float*)d_in[7];
  const float* g1w0 = (const float*)d_in[8];
  const float* g1b0 = (const float*)d_in[9];
  const float* g1w1 = (const float*)d_in[10];
  const float* g1b1 = (const float*)d_in[11];
  const float* g2w0 = (const float*)d_in[12];
  const float* g2b0 = (const float*)d_in[13];
  const float* g2w1 = (const float*)d_in[14];
  const float* g2b1 = (const float*)d_in[15];
  float* out = (float*)d_out;

  // Scratch (7.73 MB with i16 neighbor indices): prefer d_ws; fall back to
  // the local-output region of d_out (16.8 MB, overwritten by local_mlp LAST).
  const size_t NEED = 7725056;
  char* sc = (ws_size >= NEED) ? (char*)d_ws : (char*)d_out;
  float* h1   = (float*)(sc + 0);        // 4*2048*128 f32 = 4,194,304 B
  float* h2   = (float*)(sc + 4194304);  // 4*512*256 f32  = 2,097,152 B
  float* c1   = (float*)(sc + 6291456);  // 4*2048*3 f32   =    98,304 B
  float* c2   = (float*)(sc + 6389760);  // 4*512*3 f32    =    24,576 B
  short* nbr1 = (short*)(sc + 6414336);  // 4*2048*64 i16  = 1,048,576 B
  short* nbr2 = (short*)(sc + 7462912);  // 4*512*64 i16   =   262,144 B (end 7,725,056)

  fps_kernel<MM, SS1, 1024><<<BB, 1024, 0, stream>>>(pos, c1);
  nbr_kernel<MM><<<BB * SS1 / 4, 256, 0, stream>>>(pos, c1, SS1, 0.04f, nbr1);
  group1_kernel<<<BB * SS1, 256, 0, stream>>>(pos, x, c1, nbr1, g1w0, g1b0, g1w1, g1b1, h1);
  fps_kernel<SS1, SS2, 1024><<<BB, 1024, 0, stream>>>(c1, c2);
  nbr_kernel<SS1><<<BB * SS2 / 4, 256, 0, stream>>>(c1, c2, SS2, 0.16f, nbr2);
  group2_kernel<<<BB * SS2, 256, 0, stream>>>(h1, c1, c2, nbr2, g2w0, g2b0, g2w1, g2b1, h2);
  gmax_kernel<<<BB, 256, 0, stream>>>(h2, out);
  local_mlp_kernel<<<BB * MM / 2, 256, 0, stream>>>(pos, lw0, lb0, lw1, lb1, lw2, lb2, out);
}

// Round 12
// 4307.420 us; speedup vs baseline: 1.0102x; 1.0102x over previous
//
#include <hip/hip_runtime.h>
#include <hip/hip_bf16.h>

#define BB 4
#define MM 8192
#define SS1 2048
#define SS2 512

using ull = unsigned long long;

// ---------------- local branch MLP: pos -> 64 -> 64 -> 128 (tanh each) ----------------
__global__ __launch_bounds__(256) void local_mlp_kernel(
    const float* __restrict__ pos,
    const float* __restrict__ w0, const float* __restrict__ b0,
    const float* __restrict__ w1, const float* __restrict__ b1,
    const float* __restrict__ w2, const float* __restrict__ b2,
    float* __restrict__ out) {
  __shared__ float p[2][3];
  __shared__ float h0[2][64];
  __shared__ float h1[2][64];
  int t = threadIdx.x;
  size_t pid0 = (size_t)blockIdx.x * 2;
  if (t < 6) {
    int pp = t / 3, j = t % 3;
    p[pp][j] = pos[(pid0 + pp) * 3 + j];
  }
  __syncthreads();
  if (t < 128) {
    int pp = t >> 6, c = t & 63;
    float acc = b0[c];
    #pragma unroll
    for (int j = 0; j < 3; ++j) acc += p[pp][j] * w0[j * 64 + c];
    h0[pp][c] = tanhf(acc);
  }
  __syncthreads();
  if (t < 128) {
    int pp = t >> 6, c = t & 63;
    float acc = b1[c];
    #pragma unroll
    for (int j = 0; j < 64; ++j) acc += h0[pp][j] * w1[j * 64 + c];
    h1[pp][c] = tanhf(acc);
  }
  __syncthreads();
  {
    int pp = t >> 7, c = t & 127;
    float acc = b2[c];
    #pragma unroll
    for (int j = 0; j < 64; ++j) acc += h1[pp][j] * w2[j * 128 + c];
    out[(pid0 + pp) * 128 + c] = tanhf(acc);
  }
}

// ---------------- DPP helpers ----------
template <int CTRL>
__device__ __forceinline__ void dpp_max_step(ull& k) {
  unsigned lo = (unsigned)k, hi = (unsigned)(k >> 32);
  unsigned plo = (unsigned)__builtin_amdgcn_update_dpp(0, (int)lo, CTRL, 0xF, 0xF, true);
  unsigned phi = (unsigned)__builtin_amdgcn_update_dpp(0, (int)hi, CTRL, 0xF, 0xF, true);
  ull pk = ((ull)phi << 32) | plo;
  if (pk > k) k = pk;
}

// full-wave max, result in lane 63
__device__ __forceinline__ void wave_max_u64(ull& k) {
  dpp_max_step<0x111>(k);  // row_shr:1
  dpp_max_step<0x112>(k);  // row_shr:2
  dpp_max_step<0x114>(k);  // row_shr:4
  dpp_max_step<0x118>(k);  // row_shr:8
  dpp_max_step<0x142>(k);  // row_bcast:15
  dpp_max_step<0x143>(k);  // row_bcast:31 -> lane63 = wave max
}

// 16-lane (one row) max, result in lane 15
__device__ __forceinline__ void row16_max_u64(ull& k) {
  dpp_max_step<0x111>(k);
  dpp_max_step<0x112>(k);
  dpp_max_step<0x114>(k);
  dpp_max_step<0x118>(k);
}

// ---------------- farthest point sampling ----------------
// One block per batch, 1024 threads, E points/thread in REGISTERS.
// Exact f32 numpy semantics: contract off, x*x then +y*y then +z*z; argmax
// ties -> lowest index via key (d2_bits<<32)|~idx.
// THE key trick: px/py/pz originate from VOLATILE inline asm (v_mov), so the
// compiler cannot rematerialize them from global loads (R5-R11: every variant
// re-fetched ~96KB/iter from L2 because reloading const-restrict data is
// always legal; VGPR_Count 28..88 all below array size). Volatile-origin
// values must live in registers (budget 128 at launch_bounds(1024,4); ~55 needed).
template <int MP, int NSEL, int THREADS>
__global__ __launch_bounds__(THREADS, THREADS / 256) void fps_kernel(
    const float* __restrict__ pts, float* __restrict__ cen) {
  constexpr int E = MP / THREADS;
  constexpr int W = THREADS / 64;
  __shared__ ull kb[2][W];
  int t = threadIdx.x;
  int lane = t & 63, wv = t >> 6;
  int b = blockIdx.x;
  const float* p = pts + (size_t)b * MP * 3;
  float* c_out = cen + (size_t)b * NSEL * 3;
  float px[E], py[E], pz[E], dd[E];
  int base = t * E;
  #pragma unroll
  for (int e = 0; e < E; ++e) {
    float lx = p[(base + e) * 3 + 0];
    float ly = p[(base + e) * 3 + 1];
    float lz = p[(base + e) * 3 + 2];
    asm volatile("v_mov_b32 %0, %1" : "=v"(px[e]) : "v"(lx));
    asm volatile("v_mov_b32 %0, %1" : "=v"(py[e]) : "v"(ly));
    asm volatile("v_mov_b32 %0, %1" : "=v"(pz[e]) : "v"(lz));
    dd[e] = INFINITY;
  }
  float cx = p[0], cy = p[1], cz = p[2];
  if (t == 0) { c_out[0] = cx; c_out[1] = cy; c_out[2] = cz; }
  int par = 0;
  for (int it = 1; it < NSEL; ++it) {
    float bd = -1.0f;
    int bidx = 0;
    {
      #pragma clang fp contract(off)
      #pragma unroll
      for (int e = 0; e < E; ++e) {
        float dx = px[e] - cx, dy = py[e] - cy, dz = pz[e] - cz;
        float nd = dx * dx;
        nd += dy * dy;
        nd += dz * dz;
        float d = fminf(dd[e], nd);
        dd[e] = d;
        if (d > bd) { bd = d; bidx = base + e; }  // strict > keeps lowest index
      }
    }
    ull k = ((ull)__float_as_uint(bd) << 32) | (unsigned)(~bidx);
    wave_max_u64(k);
    if (lane == 63) kb[par][wv] = k;
    __syncthreads();
    ull v = 0;
    if (lane < W) v = kb[par][lane];  // one predicated ds_read_b64 per wave
    row16_max_u64(v);                 // lane15 = block max
    ull g = __shfl(v, 15, 64);
    int widx = __builtin_amdgcn_readfirstlane((int)(~(unsigned)g));
    const float* cp = p + (size_t)widx * 3;  // wave-uniform -> scalar load
    cx = cp[0]; cy = cp[1]; cz = cp[2];
    if (t == 0) {
      c_out[it * 3 + 0] = cx;
      c_out[it * 3 + 1] = cy;
      c_out[it * 3 + 2] = cz;
    }
    par ^= 1;
  }
}

// ---------------- ball query: 64 nearest with d2 <= R2, ties by lower index ----------------
// Output indices as i16 (values -1..8191 fit losslessly).
template <int MP>
__global__ __launch_bounds__(256) void nbr_kernel(const float* __restrict__ pts,
                                                  const float* __restrict__ cen, int S,
                                                  float R2, short* __restrict__ nbr) {
  constexpr int CAP = 1024;
  __shared__ ull buf[4][CAP];
  int t = threadIdx.x;
  int wv = t >> 6, lane = t & 63;
  int gw = blockIdx.x * 4 + wv;
  int b = gw / S, s = gw % S;
  const float* p = pts + (size_t)b * MP * 3;
  const float* c = cen + ((size_t)b * S + s) * 3;
  float cx = c[0], cy = c[1], cz = c[2];
  ull* bw = buf[wv];
  int cnt = 0;
  {
    #pragma clang fp contract(off)
    for (int i0 = 0; i0 < MP; i0 += 64) {
      int i = i0 + lane;
      float dx = p[i * 3 + 0] - cx;
      float dy = p[i * 3 + 1] - cy;
      float dz = p[i * 3 + 2] - cz;
      float d2 = dx * dx;
      d2 += dy * dy;
      d2 += dz * dz;
      bool in = (d2 <= R2);
      ull mask = __ballot(in);
      if (in) {
        int off = __popcll(mask & ((1ull << lane) - 1ull));
        int pos = cnt + off;
        if (pos < CAP)
          bw[pos] = ((ull)__float_as_uint(d2) << 32) | (unsigned)i;
      }
      cnt += __popcll(mask);
    }
  }
  if (cnt > CAP) cnt = CAP;
  __syncthreads();  // uniform; ensures LDS writes visible
  int out = -1;
  if (cnt <= 64) {
    if (lane < cnt) out = (int)(unsigned)bw[lane];
  } else {
    for (int r = 0; r < 64; ++r) {
      ull mk = ~0ull;
      int mj = -1;
      for (int j = lane; j < cnt; j += 64) {
        ull v = bw[j];
        if (v < mk) { mk = v; mj = j; }
      }
      ull kc = ~mk;
      wave_max_u64(kc);
      ull g = ~__shfl(kc, 63, 64);
      if (mk == g && mj >= 0) bw[mj] = ~0ull;  // unique keys -> exactly one owner
      asm volatile("s_waitcnt lgkmcnt(0)" ::: "memory");
      if (lane == r) out = (int)(unsigned)g;
    }
  }
  nbr[((size_t)b * S + s) * 64 + lane] = (short)out;
}

// ---------------- SA1 grouped MLP: feats[64][9] -> 64 -> 128, masked max over K ----------------
// layer2 register-tiled 8k x 4ch; tanh/bias deferred past the masked max (exact).
__global__ __launch_bounds__(256, 4) void group1_kernel(
    const float* __restrict__ pos, const float* __restrict__ x,
    const float* __restrict__ c1, const short* __restrict__ nbr,
    const float* __restrict__ w0, const float* __restrict__ b0,
    const float* __restrict__ w1, const float* __restrict__ b1,
    float* __restrict__ h1out) {
  __shared__ float feats[64][12];
  __shared__ float hbuf[64][68];
  __shared__ float Mred[8][128];
  __shared__ int nb[64];
  __shared__ float cc[3];
  int t = threadIdx.x;
  int bs = blockIdx.x;  // b*S1 + s
  int b = bs >> 11;
  if (t < 64) nb[t] = (int)nbr[(size_t)bs * 64 + t];
  if (t < 3) cc[t] = c1[(size_t)bs * 3 + t];
  __syncthreads();
  if (t < 64) {
    int n = nb[t];
    int ni = ((unsigned)n < (unsigned)MM) ? n : 0;  // clamp: replay-safe
    const float* pp = pos + ((size_t)b * MM + ni) * 3;
    const float* xx = x + ((size_t)b * MM + ni) * 3;
    float p0 = pp[0], p1 = pp[1], p2 = pp[2];
    feats[t][0] = p0; feats[t][1] = p1; feats[t][2] = p2;
    feats[t][3] = xx[0]; feats[t][4] = xx[1]; feats[t][5] = xx[2];
    feats[t][6] = p0 - cc[0]; feats[t][7] = p1 - cc[1]; feats[t][8] = p2 - cc[2];
  }
  __syncthreads();
  // layer1: 9 -> 64; thread (k = t>>2, q = t&3) computes 16 channels
  {
    int k = t >> 2, q = t & 3;
    float acc[16];
    #pragma unroll
    for (int i = 0; i < 16; ++i) acc[i] = b0[q * 16 + i];
    #pragma unroll
    for (int j = 0; j < 9; ++j) {
      float f = feats[k][j];
      const float4* wr = (const float4*)(w0 + j * 64 + q * 16);
      #pragma unroll
      for (int i = 0; i < 4; ++i) {
        float4 wvv = wr[i];
        acc[4 * i + 0] += f * wvv.x;
        acc[4 * i + 1] += f * wvv.y;
        acc[4 * i + 2] += f * wvv.z;
        acc[4 * i + 3] += f * wvv.w;
      }
    }
    #pragma unroll
    for (int i = 0; i < 16; ++i) hbuf[k][q * 16 + i] = tanhf(acc[i]);
  }
  __syncthreads();
  // layer2: hidden[64][64] x W1[64][128], masked PRE-ACT max over k
  {
    int kt = t >> 5;  // 0..7
    int ct = t & 31;  // 0..31
    float acc[8][4];
    #pragma unroll
    for (int a = 0; a < 8; ++a)
      #pragma unroll
      for (int ci = 0; ci < 4; ++ci) acc[a][ci] = 0.f;
    const float* wbase = w1 + ct * 4;
    for (int j = 0; j < 64; j += 2) {
      float2 fv[8];
      #pragma unroll
      for (int kk = 0; kk < 8; ++kk)
        fv[kk] = *(const float2*)&hbuf[kt * 8 + kk][j];
      float wja[4], wjb[4];
      *(float4*)&wja[0] = *(const float4*)(wbase + (size_t)j * 128);
      *(float4*)&wjb[0] = *(const float4*)(wbase + (size_t)(j + 1) * 128);
      #pragma unroll
      for (int kk = 0; kk < 8; ++kk)
        #pragma unroll
        for (int ci = 0; ci < 4; ++ci) {
          acc[kk][ci] += fv[kk].x * wja[ci];
          acc[kk][ci] += fv[kk].y * wjb[ci];
        }
    }
    float m[4];
    #pragma unroll
    for (int ci = 0; ci < 4; ++ci) m[ci] = -INFINITY;
    #pragma unroll
    for (int kk = 0; kk < 8; ++kk) {
      if (nb[kt * 8 + kk] >= 0) {
        #pragma unroll
        for (int ci = 0; ci < 4; ++ci) m[ci] = fmaxf(m[ci], acc[kk][ci]);
      }
    }
    #pragma unroll
    for (int ci = 0; ci < 4; ++ci) Mred[kt][ct * 4 + ci] = m[ci];
  }
  __syncthreads();
  if (t < 128) {
    float mx = Mred[0][t];
    #pragma unroll
    for (int r = 1; r < 8; ++r) mx = fmaxf(mx, Mred[r][t]);
    h1out[(size_t)bs * 128 + t] = tanhf(mx + b1[t]);  // bias+tanh after max: exact
  }
}

// ---------------- SA2 grouped MLP: feats[64][131] -> 128 -> 256, masked max over K ----------------
__global__ __launch_bounds__(256, 4) void group2_kernel(
    const float* __restrict__ h1, const float* __restrict__ c1,
    const float* __restrict__ c2, const short* __restrict__ nbr,
    const float* __restrict__ w0, const float* __restrict__ b0,
    const float* __restrict__ w1, const float* __restrict__ b1,
    float* __restrict__ h2out) {
  __shared__ float fb[64][132];  // feats (131) then reused as hidden (128)
  __shared__ float Mred[8][256];
  __shared__ int nb[64];
  __shared__ float cc[3];
  int t = threadIdx.x;
  int bs = blockIdx.x;  // b*S2 + s
  int b = bs >> 9;
  if (t < 64) nb[t] = (int)nbr[(size_t)bs * 64 + t];
  if (t < 3) cc[t] = c2[(size_t)bs * 3 + t];
  __syncthreads();
  {
    int k = t >> 2, q = t & 3;
    int n = nb[k];
    int ni = ((unsigned)n < (unsigned)SS1) ? n : 0;  // clamp: replay-safe
    const float* hrow = h1 + ((size_t)b * SS1 + ni) * 128;
    #pragma unroll
    for (int i = 0; i < 32; ++i) fb[k][q * 32 + i] = hrow[q * 32 + i];
    if (q == 0) {
      const float* pr = c1 + ((size_t)b * SS1 + ni) * 3;
      fb[k][128] = pr[0] - cc[0];
      fb[k][129] = pr[1] - cc[1];
      fb[k][130] = pr[2] - cc[2];
    }
  }
  __syncthreads();
  float acc1[32];
  {
    int k = t >> 2, q = t & 3;
    #pragma unroll
    for (int i = 0; i < 32; ++i) acc1[i] = b0[q * 32 + i];
    for (int j = 0; j < 131; ++j) {
      float f = fb[k][j];
      const float4* wr = (const float4*)(w0 + (size_t)j * 128 + q * 32);
      #pragma unroll
      for (int i = 0; i < 8; ++i) {
        float4 wvv = wr[i];
        acc1[4 * i + 0] += f * wvv.x;
        acc1[4 * i + 1] += f * wvv.y;
        acc1[4 * i + 2] += f * wvv.z;
        acc1[4 * i + 3] += f * wvv.w;
      }
    }
  }
  __syncthreads();
  {
    int k = t >> 2, q = t & 3;
    #pragma unroll
    for (int i = 0; i < 32; ++i) fb[k][q * 32 + i] = tanhf(acc1[i]);
  }
  __syncthreads();
  {
    int kt = t >> 5;  // 0..7
    int ct = t & 31;  // 0..31
    float acc[8][8];
    #pragma unroll
    for (int a = 0; a < 8; ++a)
      #pragma unroll
      for (int c2i = 0; c2i < 8; ++c2i) acc[a][c2i] = 0.f;
    const float* wbase = w1 + ct * 8;
    for (int j = 0; j < 128; j += 2) {
      float2 fv[8];
      #pragma unroll
      for (int kk = 0; kk < 8; ++kk)
        fv[kk] = *(const float2*)&fb[kt * 8 + kk][j];
      float wja[8], wjb[8];
      const float4* wp0 = (const float4*)(wbase + (size_t)j * 256);
      const float4* wp1 = (const float4*)(wbase + (size_t)(j + 1) * 256);
      *(float4*)&wja[0] = wp0[0];
      *(float4*)&wja[4] = wp0[1];
      *(float4*)&wjb[0] = wp1[0];
      *(float4*)&wjb[4] = wp1[1];
      #pragma unroll
      for (int kk = 0; kk < 8; ++kk)
        #pragma unroll
        for (int ci = 0; ci < 8; ++ci) {
          acc[kk][ci] += fv[kk].x * wja[ci];
          acc[kk][ci] += fv[kk].y * wjb[ci];
        }
    }
    float m[8];
    #pragma unroll
    for (int ci = 0; ci < 8; ++ci) m[ci] = -INFINITY;
    #pragma unroll
    for (int kk = 0; kk < 8; ++kk) {
      if (nb[kt * 8 + kk] >= 0) {
        #pragma unroll
        for (int ci = 0; ci < 8; ++ci) m[ci] = fmaxf(m[ci], acc[kk][ci]);
      }
    }
    #pragma unroll
    for (int ci = 0; ci < 8; ++ci) Mred[kt][ct * 8 + ci] = m[ci];
  }
  __syncthreads();
  if (t < 256) {
    float mx = Mred[0][t];
    #pragma unroll
    for (int r = 1; r < 8; ++r) mx = fmaxf(mx, Mred[r][t]);
    h2out[(size_t)bs * 256 + t] = tanhf(mx + b1[t]);  // bias+tanh after max: exact
  }
}

// ---------------- global max over centers ----------------
__global__ __launch_bounds__(256) void gmax_kernel(const float* __restrict__ h2,
                                                   float* __restrict__ out) {
  int b = blockIdx.x, c = threadIdx.x;
  float mx = -INFINITY;
  for (int s = 0; s < SS2; ++s)
    mx = fmaxf(mx, h2[((size_t)b * SS2 + s) * 256 + c]);
  out[(size_t)BB * MM * 128 + b * 256 + c] = mx;
}

extern "C" void kernel_launch(void* const* d_in, const int* in_sizes, int n_in,
                              void* d_out, int out_size, void* d_ws, size_t ws_size,
                              hipStream_t stream) {
  // Reference is pure float32: all inputs AND the output buffer are f32.
  const float* x    = (const float*)d_in[0];
  const float* pos  = (const float*)d_in[1];
  const float* lw0  = (const float*)d_in[2];
  const float* lb0  = (const float*)d_in[3];
  const float* lw1  = (const float*)d_in[4];
  const float* lb1  = (const float*)d_in[5];
  const float* lw2  = (const float*)d_in[6];
  const float* lb2  = (const float*)d_in[7];
  const float* g1w0 = (const float*)d_in[8];
  const float* g1b0 = (const float*)d_in[9];
  const float* g1w1 = (const float*)d_in[10];
  const float* g1b1 = (const float*)d_in[11];
  const float* g2w0 = (const float*)d_in[12];
  const float* g2b0 = (const float*)d_in[13];
  const float* g2w1 = (const float*)d_in[14];
  const float* g2b1 = (const float*)d_in[15];
  float* out = (float*)d_out;

  // Scratch (7.73 MB with i16 neighbor indices): prefer d_ws; fall back to
  // the local-output region of d_out (16.8 MB, overwritten by local_mlp LAST).
  const size_t NEED = 7725056;
  char* sc = (ws_size >= NEED) ? (char*)d_ws : (char*)d_out;
  float* h1   = (float*)(sc + 0);        // 4*2048*128 f32 = 4,194,304 B
  float* h2   = (float*)(sc + 4194304);  // 4*512*256 f32  = 2,097,152 B
  float* c1   = (float*)(sc + 6291456);  // 4*2048*3 f32   =    98,304 B
  float* c2   = (float*)(sc + 6389760);  // 4*512*3 f32    =    24,576 B
  short* nbr1 = (short*)(sc + 6414336);  // 4*2048*64 i16  = 1,048,576 B
  short* nbr2 = (short*)(sc + 7462912);  // 4*512*64 i16   =   262,144 B (end 7,725,056)

  fps_kernel<MM, SS1, 1024><<<BB, 1024, 0, stream>>>(pos, c1);
  nbr_kernel<MM><<<BB * SS1 / 4, 256, 0, stream>>>(pos, c1, SS1, 0.04f, nbr1);
  group1_kernel<<<BB * SS1, 256, 0, stream>>>(pos, x, c1, nbr1, g1w0, g1b0, g1w1, g1b1, h1);
  fps_kernel<SS1, SS2, 1024><<<BB, 1024, 0, stream>>>(c1, c2);
  nbr_kernel<SS1><<<BB * SS2 / 4, 256, 0, stream>>>(c1, c2, SS2, 0.16f, nbr2);
  group2_kernel<<<BB * SS2, 256, 0, stream>>>(h1, c1, c2, nbr2, g2w0, g2b0, g2w1, g2b1, h2);
  gmax_kernel<<<BB, 256, 0, stream>>>(h2, out);
  local_mlp_kernel<<<BB * MM / 2, 256, 0, stream>>>(pos, lw0, lb0, lw1, lb1, lw2, lb2, out);
}

// Round 13
// 4244.623 us; speedup vs baseline: 1.0251x; 1.0148x over previous
//
#include <hip/hip_runtime.h>
#include <hip/hip_bf16.h>

#define BB 4
#define MM 8192
#define SS1 2048
#define SS2 512

using ull = unsigned long long;

// ---------------- local branch MLP: pos -> 64 -> 64 -> 128 (tanh each) ----------------
// 4 points per 256-thread block: layers 1-2 use all 256 threads (was 50%).
__global__ __launch_bounds__(256) void local_mlp_kernel(
    const float* __restrict__ pos,
    const float* __restrict__ w0, const float* __restrict__ b0,
    const float* __restrict__ w1, const float* __restrict__ b1,
    const float* __restrict__ w2, const float* __restrict__ b2,
    float* __restrict__ out) {
  __shared__ float p[4][3];
  __shared__ float h0[4][64];
  __shared__ float h1[4][64];
  int t = threadIdx.x;
  size_t pid0 = (size_t)blockIdx.x * 4;
  if (t < 12) {
    int pp = t / 3, j = t % 3;
    p[pp][j] = pos[(pid0 + pp) * 3 + j];
  }
  __syncthreads();
  {
    int pp = t >> 6, c = t & 63;
    float acc = b0[c];
    #pragma unroll
    for (int j = 0; j < 3; ++j) acc += p[pp][j] * w0[j * 64 + c];
    h0[pp][c] = tanhf(acc);
  }
  __syncthreads();
  {
    int pp = t >> 6, c = t & 63;
    float acc = b1[c];
    #pragma unroll
    for (int j = 0; j < 64; ++j) acc += h0[pp][j] * w1[j * 64 + c];
    h1[pp][c] = tanhf(acc);
  }
  __syncthreads();
  #pragma unroll
  for (int r = 0; r < 2; ++r) {
    int o = t + 256 * r;
    int pp = o >> 7, c = o & 127;
    float acc = b2[c];
    #pragma unroll
    for (int j = 0; j < 64; ++j) acc += h1[pp][j] * w2[j * 128 + c];
    out[(pid0 + pp) * 128 + c] = tanhf(acc);
  }
}

// ---------------- DPP helpers ----------
template <int CTRL>
__device__ __forceinline__ void dpp_max_step(ull& k) {
  unsigned lo = (unsigned)k, hi = (unsigned)(k >> 32);
  unsigned plo = (unsigned)__builtin_amdgcn_update_dpp(0, (int)lo, CTRL, 0xF, 0xF, true);
  unsigned phi = (unsigned)__builtin_amdgcn_update_dpp(0, (int)hi, CTRL, 0xF, 0xF, true);
  ull pk = ((ull)phi << 32) | plo;
  if (pk > k) k = pk;
}

// full-wave max, result in lane 63
__device__ __forceinline__ void wave_max_u64(ull& k) {
  dpp_max_step<0x111>(k);  // row_shr:1
  dpp_max_step<0x112>(k);  // row_shr:2
  dpp_max_step<0x114>(k);  // row_shr:4
  dpp_max_step<0x118>(k);  // row_shr:8
  dpp_max_step<0x142>(k);  // row_bcast:15
  dpp_max_step<0x143>(k);  // row_bcast:31 -> lane63 = wave max
}

// 16-lane (one row) max, result in lane 15
__device__ __forceinline__ void row16_max_u64(ull& k) {
  dpp_max_step<0x111>(k);
  dpp_max_step<0x112>(k);
  dpp_max_step<0x114>(k);
  dpp_max_step<0x118>(k);
}

// ---------------- farthest point sampling ----------------
// One block per batch. Exact f32 numpy semantics: contract off, x*x then
// +y*y then +z*z; argmax ties -> lowest index via key (d2_bits<<32)|~idx
// (mapping-agnostic, so the strided element mapping below is safe).
// Register residency for the point arrays is unachievable (R5-R12: allocator
// remats from global or spills volatile-asm values to scratch; VGPR 28..88).
// Instead: points in LDS as float4 -> ONE ds_read_b128 per element per iter
// (R9/R10's 2-3 DS ops/elem were issue-bound at ~2600-3000 cyc/iter).
// Lane-stride 16B is the canonical conflict-free b128 pattern.
template <int MP, int NSEL, int THREADS>
__global__ __launch_bounds__(THREADS, 1) void fps_kernel(
    const float* __restrict__ pts, float* __restrict__ cen) {
  constexpr int E = MP / THREADS;
  constexpr int W = THREADS / 64;
  __shared__ float4 sp[MP];  // 16 B/point; 128 KB at MP=8192 (<= 160 KB/CU)
  __shared__ ull kb[2][W];
  int t = threadIdx.x;
  int lane = t & 63, wv = t >> 6;
  int b = blockIdx.x;
  const float* p = pts + (size_t)b * MP * 3;
  float* c_out = cen + (size_t)b * NSEL * 3;
  for (int i = t; i < MP; i += THREADS)
    sp[i] = make_float4(p[i * 3 + 0], p[i * 3 + 1], p[i * 3 + 2], 0.f);
  float dd[E];
  #pragma unroll
  for (int e = 0; e < E; ++e) dd[e] = INFINITY;
  __syncthreads();
  float4 c0 = sp[0];
  float cx = c0.x, cy = c0.y, cz = c0.z;
  if (t == 0) { c_out[0] = cx; c_out[1] = cy; c_out[2] = cz; }
  int par = 0;
  for (int it = 1; it < NSEL; ++it) {
    float bd = -1.0f;
    int bidx = 0;
    {
      #pragma clang fp contract(off)
      #pragma unroll
      for (int e = 0; e < E; ++e) {
        int i = t + e * THREADS;
        float4 q = sp[i];  // one ds_read_b128
        float dx = q.x - cx, dy = q.y - cy, dz = q.z - cz;
        float nd = dx * dx;
        nd += dy * dy;
        nd += dz * dz;
        float d = fminf(dd[e], nd);
        dd[e] = d;
        if (d > bd) { bd = d; bidx = i; }  // strict > keeps lowest index in-thread
      }
    }
    ull k = ((ull)__float_as_uint(bd) << 32) | (unsigned)(~bidx);
    wave_max_u64(k);
    if (lane == 63) kb[par][wv] = k;
    __syncthreads();
    ull v = 0;
    if (lane < W) v = kb[par][lane];  // one predicated ds_read_b64 per wave
    row16_max_u64(v);                 // lane15 >= block max (W<=16)
    ull g = __shfl(v, 15, 64);
    int widx = (int)(~(unsigned)g) & (MP - 1);  // clamp: replay-safe no-op
    float4 cw = sp[widx];  // uniform address -> LDS broadcast
    cx = cw.x; cy = cw.y; cz = cw.z;
    if (t == 0) {
      c_out[it * 3 + 0] = cx;
      c_out[it * 3 + 1] = cy;
      c_out[it * 3 + 2] = cz;
    }
    par ^= 1;
  }
}

// ---------------- ball query: 64 nearest with d2 <= R2, ties by lower index ----------------
// Output indices as i16 (values -1..8191 fit losslessly).
template <int MP>
__global__ __launch_bounds__(256) void nbr_kernel(const float* __restrict__ pts,
                                                  const float* __restrict__ cen, int S,
                                                  float R2, short* __restrict__ nbr) {
  constexpr int CAP = 1024;
  __shared__ ull buf[4][CAP];
  int t = threadIdx.x;
  int wv = t >> 6, lane = t & 63;
  int gw = blockIdx.x * 4 + wv;
  int b = gw / S, s = gw % S;
  const float* p = pts + (size_t)b * MP * 3;
  const float* c = cen + ((size_t)b * S + s) * 3;
  float cx = c[0], cy = c[1], cz = c[2];
  ull* bw = buf[wv];
  int cnt = 0;
  {
    #pragma clang fp contract(off)
    for (int i0 = 0; i0 < MP; i0 += 64) {
      int i = i0 + lane;
      float dx = p[i * 3 + 0] - cx;
      float dy = p[i * 3 + 1] - cy;
      float dz = p[i * 3 + 2] - cz;
      float d2 = dx * dx;
      d2 += dy * dy;
      d2 += dz * dz;
      bool in = (d2 <= R2);
      ull mask = __ballot(in);
      if (in) {
        int off = __popcll(mask & ((1ull << lane) - 1ull));
        int pos = cnt + off;
        if (pos < CAP)
          bw[pos] = ((ull)__float_as_uint(d2) << 32) | (unsigned)i;
      }
      cnt += __popcll(mask);
    }
  }
  if (cnt > CAP) cnt = CAP;
  __syncthreads();  // uniform; ensures LDS writes visible
  int out = -1;
  if (cnt <= 64) {
    if (lane < cnt) out = (int)(unsigned)bw[lane];
  } else {
    for (int r = 0; r < 64; ++r) {
      ull mk = ~0ull;
      int mj = -1;
      for (int j = lane; j < cnt; j += 64) {
        ull v = bw[j];
        if (v < mk) { mk = v; mj = j; }
      }
      ull kc = ~mk;
      wave_max_u64(kc);
      ull g = ~__shfl(kc, 63, 64);
      if (mk == g && mj >= 0) bw[mj] = ~0ull;  // unique keys -> exactly one owner
      asm volatile("s_waitcnt lgkmcnt(0)" ::: "memory");
      if (lane == r) out = (int)(unsigned)g;
    }
  }
  nbr[((size_t)b * S + s) * 64 + lane] = (short)out;
}

// ---------------- SA1 grouped MLP: feats[64][9] -> 64 -> 128, masked max over K ----------------
// layer2 register-tiled 8k x 4ch; tanh/bias deferred past the masked max (exact).
__global__ __launch_bounds__(256, 4) void group1_kernel(
    const float* __restrict__ pos, const float* __restrict__ x,
    const float* __restrict__ c1, const short* __restrict__ nbr,
    const float* __restrict__ w0, const float* __restrict__ b0,
    const float* __restrict__ w1, const float* __restrict__ b1,
    float* __restrict__ h1out) {
  __shared__ float feats[64][12];
  __shared__ float hbuf[64][68];
  __shared__ float Mred[8][128];
  __shared__ int nb[64];
  __shared__ float cc[3];
  int t = threadIdx.x;
  int bs = blockIdx.x;  // b*S1 + s
  int b = bs >> 11;
  if (t < 64) nb[t] = (int)nbr[(size_t)bs * 64 + t];
  if (t < 3) cc[t] = c1[(size_t)bs * 3 + t];
  __syncthreads();
  if (t < 64) {
    int n = nb[t];
    int ni = ((unsigned)n < (unsigned)MM) ? n : 0;  // clamp: replay-safe
    const float* pp = pos + ((size_t)b * MM + ni) * 3;
    const float* xx = x + ((size_t)b * MM + ni) * 3;
    float p0 = pp[0], p1 = pp[1], p2 = pp[2];
    feats[t][0] = p0; feats[t][1] = p1; feats[t][2] = p2;
    feats[t][3] = xx[0]; feats[t][4] = xx[1]; feats[t][5] = xx[2];
    feats[t][6] = p0 - cc[0]; feats[t][7] = p1 - cc[1]; feats[t][8] = p2 - cc[2];
  }
  __syncthreads();
  // layer1: 9 -> 64; thread (k = t>>2, q = t&3) computes 16 channels
  {
    int k = t >> 2, q = t & 3;
    float acc[16];
    #pragma unroll
    for (int i = 0; i < 16; ++i) acc[i] = b0[q * 16 + i];
    #pragma unroll
    for (int j = 0; j < 9; ++j) {
      float f = feats[k][j];
      const float4* wr = (const float4*)(w0 + j * 64 + q * 16);
      #pragma unroll
      for (int i = 0; i < 4; ++i) {
        float4 wvv = wr[i];
        acc[4 * i + 0] += f * wvv.x;
        acc[4 * i + 1] += f * wvv.y;
        acc[4 * i + 2] += f * wvv.z;
        acc[4 * i + 3] += f * wvv.w;
      }
    }
    #pragma unroll
    for (int i = 0; i < 16; ++i) hbuf[k][q * 16 + i] = tanhf(acc[i]);
  }
  __syncthreads();
  // layer2: hidden[64][64] x W1[64][128], masked PRE-ACT max over k
  {
    int kt = t >> 5;  // 0..7
    int ct = t & 31;  // 0..31
    float acc[8][4];
    #pragma unroll
    for (int a = 0; a < 8; ++a)
      #pragma unroll
      for (int ci = 0; ci < 4; ++ci) acc[a][ci] = 0.f;
    const float* wbase = w1 + ct * 4;
    for (int j = 0; j < 64; j += 2) {
      float2 fv[8];
      #pragma unroll
      for (int kk = 0; kk < 8; ++kk)
        fv[kk] = *(const float2*)&hbuf[kt * 8 + kk][j];
      float wja[4], wjb[4];
      *(float4*)&wja[0] = *(const float4*)(wbase + (size_t)j * 128);
      *(float4*)&wjb[0] = *(const float4*)(wbase + (size_t)(j + 1) * 128);
      #pragma unroll
      for (int kk = 0; kk < 8; ++kk)
        #pragma unroll
        for (int ci = 0; ci < 4; ++ci) {
          acc[kk][ci] += fv[kk].x * wja[ci];
          acc[kk][ci] += fv[kk].y * wjb[ci];
        }
    }
    float m[4];
    #pragma unroll
    for (int ci = 0; ci < 4; ++ci) m[ci] = -INFINITY;
    #pragma unroll
    for (int kk = 0; kk < 8; ++kk) {
      if (nb[kt * 8 + kk] >= 0) {
        #pragma unroll
        for (int ci = 0; ci < 4; ++ci) m[ci] = fmaxf(m[ci], acc[kk][ci]);
      }
    }
    #pragma unroll
    for (int ci = 0; ci < 4; ++ci) Mred[kt][ct * 4 + ci] = m[ci];
  }
  __syncthreads();
  if (t < 128) {
    float mx = Mred[0][t];
    #pragma unroll
    for (int r = 1; r < 8; ++r) mx = fmaxf(mx, Mred[r][t]);
    h1out[(size_t)bs * 128 + t] = tanhf(mx + b1[t]);  // bias+tanh after max: exact
  }
}

// ---------------- SA2 grouped MLP: feats[64][131] -> 128 -> 256, masked max over K ----------------
__global__ __launch_bounds__(256, 4) void group2_kernel(
    const float* __restrict__ h1, const float* __restrict__ c1,
    const float* __restrict__ c2, const short* __restrict__ nbr,
    const float* __restrict__ w0, const float* __restrict__ b0,
    const float* __restrict__ w1, const float* __restrict__ b1,
    float* __restrict__ h2out) {
  __shared__ float fb[64][132];  // feats (131) then reused as hidden (128)
  __shared__ float Mred[8][256];
  __shared__ int nb[64];
  __shared__ float cc[3];
  int t = threadIdx.x;
  int bs = blockIdx.x;  // b*S2 + s
  int b = bs >> 9;
  if (t < 64) nb[t] = (int)nbr[(size_t)bs * 64 + t];
  if (t < 3) cc[t] = c2[(size_t)bs * 3 + t];
  __syncthreads();
  {
    int k = t >> 2, q = t & 3;
    int n = nb[k];
    int ni = ((unsigned)n < (unsigned)SS1) ? n : 0;  // clamp: replay-safe
    const float* hrow = h1 + ((size_t)b * SS1 + ni) * 128;
    #pragma unroll
    for (int i = 0; i < 32; ++i) fb[k][q * 32 + i] = hrow[q * 32 + i];
    if (q == 0) {
      const float* pr = c1 + ((size_t)b * SS1 + ni) * 3;
      fb[k][128] = pr[0] - cc[0];
      fb[k][129] = pr[1] - cc[1];
      fb[k][130] = pr[2] - cc[2];
    }
  }
  __syncthreads();
  float acc1[32];
  {
    int k = t >> 2, q = t & 3;
    #pragma unroll
    for (int i = 0; i < 32; ++i) acc1[i] = b0[q * 32 + i];
    for (int j = 0; j < 131; ++j) {
      float f = fb[k][j];
      const float4* wr = (const float4*)(w0 + (size_t)j * 128 + q * 32);
      #pragma unroll
      for (int i = 0; i < 8; ++i) {
        float4 wvv = wr[i];
        acc1[4 * i + 0] += f * wvv.x;
        acc1[4 * i + 1] += f * wvv.y;
        acc1[4 * i + 2] += f * wvv.z;
        acc1[4 * i + 3] += f * wvv.w;
      }
    }
  }
  __syncthreads();
  {
    int k = t >> 2, q = t & 3;
    #pragma unroll
    for (int i = 0; i < 32; ++i) fb[k][q * 32 + i] = tanhf(acc1[i]);
  }
  __syncthreads();
  {
    int kt = t >> 5;  // 0..7
    int ct = t & 31;  // 0..31
    float acc[8][8];
    #pragma unroll
    for (int a = 0; a < 8; ++a)
      #pragma unroll
      for (int c2i = 0; c2i < 8; ++c2i) acc[a][c2i] = 0.f;
    const float* wbase = w1 + ct * 8;
    for (int j = 0; j < 128; j += 2) {
      float2 fv[8];
      #pragma unroll
      for (int kk = 0; kk < 8; ++kk)
        fv[kk] = *(const float2*)&fb[kt * 8 + kk][j];
      float wja[8], wjb[8];
      const float4* wp0 = (const float4*)(wbase + (size_t)j * 256);
      const float4* wp1 = (const float4*)(wbase + (size_t)(j + 1) * 256);
      *(float4*)&wja[0] = wp0[0];
      *(float4*)&wja[4] = wp0[1];
      *(float4*)&wjb[0] = wp1[0];
      *(float4*)&wjb[4] = wp1[1];
      #pragma unroll
      for (int kk = 0; kk < 8; ++kk)
        #pragma unroll
        for (int ci = 0; ci < 8; ++ci) {
          acc[kk][ci] += fv[kk].x * wja[ci];
          acc[kk][ci] += fv[kk].y * wjb[ci];
        }
    }
    float m[8];
    #pragma unroll
    for (int ci = 0; ci < 8; ++ci) m[ci] = -INFINITY;
    #pragma unroll
    for (int kk = 0; kk < 8; ++kk) {
      if (nb[kt * 8 + kk] >= 0) {
        #pragma unroll
        for (int ci = 0; ci < 8; ++ci) m[ci] = fmaxf(m[ci], acc[kk][ci]);
      }
    }
    #pragma unroll
    for (int ci = 0; ci < 8; ++ci) Mred[kt][ct * 8 + ci] = m[ci];
  }
  __syncthreads();
  if (t < 256) {
    float mx = Mred[0][t];
    #pragma unroll
    for (int r = 1; r < 8; ++r) mx = fmaxf(mx, Mred[r][t]);
    h2out[(size_t)bs * 256 + t] = tanhf(mx + b1[t]);  // bias+tanh after max: exact
  }
}

// ---------------- global max over centers ----------------
__global__ __launch_bounds__(256) void gmax_kernel(const float* __restrict__ h2,
                                                   float* __restrict__ out) {
  int b = blockIdx.x, c = threadIdx.x;
  float mx = -INFINITY;
  for (int s = 0; s < SS2; ++s)
    mx = fmaxf(mx, h2[((size_t)b * SS2 + s) * 256 + c]);
  out[(size_t)BB * MM * 128 + b * 256 + c] = mx;
}

extern "C" void kernel_launch(void* const* d_in, const int* in_sizes, int n_in,
                              void* d_out, int out_size, void* d_ws, size_t ws_size,
                              hipStream_t stream) {
  // Reference is pure float32: all inputs AND the output buffer are f32.
  const float* x    = (const float*)d_in[0];
  const float* pos  = (const float*)d_in[1];
  const float* lw0  = (const float*)d_in[2];
  const float* lb0  = (const float*)d_in[3];
  const float* lw1  = (const float*)d_in[4];
  const float* lb1  = (const float*)d_in[5];
  const float* lw2  = (const float*)d_in[6];
  const float* lb2  = (const float*)d_in[7];
  const float* g1w0 = (const float*)d_in[8];
  const float* g1b0 = (const float*)d_in[9];
  const float* g1w1 = (const float*)d_in[10];
  const float* g1b1 = (const float*)d_in[11];
  const float* g2w0 = (const float*)d_in[12];
  const float* g2b0 = (const float*)d_in[13];
  const float* g2w1 = (const float*)d_in[14];
  const float* g2b1 = (const float*)d_in[15];
  float* out = (float*)d_out;

  // Scratch (7.73 MB with i16 neighbor indices): prefer d_ws; fall back to
  // the local-output region of d_out (16.8 MB, overwritten by local_mlp LAST).
  const size_t NEED = 7725056;
  char* sc = (ws_size >= NEED) ? (char*)d_ws : (char*)d_out;
  float* h1   = (float*)(sc + 0);        // 4*2048*128 f32 = 4,194,304 B
  float* h2   = (float*)(sc + 4194304);  // 4*512*256 f32  = 2,097,152 B
  float* c1   = (float*)(sc + 6291456);  // 4*2048*3 f32   =    98,304 B
  float* c2   = (float*)(sc + 6389760);  // 4*512*3 f32    =    24,576 B
  short* nbr1 = (short*)(sc + 6414336);  // 4*2048*64 i16  = 1,048,576 B
  short* nbr2 = (short*)(sc + 7462912);  // 4*512*64 i16   =   262,144 B (end 7,725,056)

  fps_kernel<MM, SS1, 512><<<BB, 512, 0, stream>>>(pos, c1);
  nbr_kernel<MM><<<BB * SS1 / 4, 256, 0, stream>>>(pos, c1, SS1, 0.04f, nbr1);
  group1_kernel<<<BB * SS1, 256, 0, stream>>>(pos, x, c1, nbr1, g1w0, g1b0, g1w1, g1b1, h1);
  fps_kernel<SS1, SS2, 512><<<BB, 512, 0, stream>>>(c1, c2);
  nbr_kernel<SS1><<<BB * SS2 / 4, 256, 0, stream>>>(c1, c2, SS2, 0.16f, nbr2);
  group2_kernel<<<BB * SS2, 256, 0, stream>>>(h1, c1, c2, nbr2, g2w0, g2b0, g2w1, g2b1, h2);
  gmax_kernel<<<BB, 256, 0, stream>>>(h2, out);
  local_mlp_kernel<<<BB * MM / 4, 256, 0, stream>>>(pos, lw0, lb0, lw1, lb1, lw2, lb2, out);
}